// Round 13
// baseline (2080.624 us; speedup 1.0000x reference)
//
#include <hip/hip_runtime.h>
#include <hip/hip_bf16.h>
#include <stdint.h>

#define B_   64
#define T_   256
#define KIN  2048
#define N3   3072
#define M_   16384
#define RBLK 256      // recurrence blocks: 4 bg x 64 cg
#define RTHR 256      // 4 waves

typedef __attribute__((ext_vector_type(8))) short short8;
typedef __attribute__((ext_vector_type(4))) float f32x4;
typedef unsigned long long u64;

static __device__ __forceinline__ float bf2f(short s) {
    union { float f; uint32_t u; } c; c.u = ((uint32_t)(uint16_t)s) << 16; return c.f;
}
static __device__ __forceinline__ float u16tof(uint32_t u) {
    union { float f; uint32_t x; } c; c.x = u << 16; return c.f;
}
static __device__ __forceinline__ short f2bf(float f) {
    union { float f; uint32_t u; } c; c.f = f;
    uint32_t u = c.u;
    uint32_t r = (u + 0x7fffu + ((u >> 16) & 1u)) >> 16;   // round-nearest-even
    return (short)(uint16_t)r;
}

// coherent (L3 coherence point) asm memory ops
#define CLDC(dst, ptr) asm volatile("global_load_dwordx4 %0, %1, off sc0 sc1" : "=v"(dst) : "v"(ptr))
#define CLDU16(dst, ptr) asm volatile("global_load_ushort %0, %1, off"        : "=v"(dst) : "v"(ptr))
static __device__ __forceinline__ void cst8(void* p, u64 v) {
    asm volatile("global_store_dwordx2 %0, %1, off sc0 sc1" :: "v"(p), "v"(v) : "memory");
}

// ---------------- prep: weights -> bf16 transposed layouts ----------------
__global__ __launch_bounds__(256)
void k_prep_w(const float* __restrict__ Wr, const float* __restrict__ Ur, const float* __restrict__ Cr,
              const float* __restrict__ Wz, const float* __restrict__ Uz, const float* __restrict__ Cz,
              const float* __restrict__ Wc, const float* __restrict__ Uc, const float* __restrict__ Cc,
              short* __restrict__ WcatT, short* __restrict__ UcatT, short* __restrict__ UcT)
{
    __shared__ float tile[32][33];
    int m = blockIdx.z;
    const float* src; short* dst; int ld, noff, koff;
    switch (m) {
      case 0: src=Cr; dst=WcatT; ld=KIN;  noff=0;    koff=0;    break;
      case 1: src=Wr; dst=WcatT; ld=KIN;  noff=0;    koff=1024; break;
      case 2: src=Cz; dst=WcatT; ld=KIN;  noff=1024; koff=0;    break;
      case 3: src=Wz; dst=WcatT; ld=KIN;  noff=1024; koff=1024; break;
      case 4: src=Cc; dst=WcatT; ld=KIN;  noff=2048; koff=0;    break;
      case 5: src=Wc; dst=WcatT; ld=KIN;  noff=2048; koff=1024; break;
      case 6: src=Ur; dst=UcatT; ld=1024; noff=0;    koff=0;    break;
      case 7: src=Uz; dst=UcatT; ld=1024; noff=1024; koff=0;    break;
      default: src=Uc; dst=UcT;  ld=1024; noff=0;    koff=0;    break;
    }
    int n0 = blockIdx.x * 32, k0 = blockIdx.y * 32;
    int tx = threadIdx.x, ty = threadIdx.y;      // block (32,8)
    #pragma unroll
    for (int i = 0; i < 32; i += 8)
        tile[ty + i][tx] = src[(long)(k0 + ty + i) * 1024 + (n0 + tx)];
    __syncthreads();
    #pragma unroll
    for (int i = 0; i < 32; i += 8)
        dst[(long)(noff + n0 + ty + i) * ld + koff + k0 + tx] = f2bf(tile[tx][ty + i]);
}

// ---------------- prep: X -> bf16 ----------------
__global__ __launch_bounds__(256)
void k_prep_x(const float* __restrict__ X, short* __restrict__ Xb, long n8)
{
    long i = (long)blockIdx.x * blockDim.x + threadIdx.x;
    long stride = (long)gridDim.x * blockDim.x;
    for (; i < n8; i += stride) {
        const float4* p = (const float4*)(X + i * 8);
        float4 a = p[0], b = p[1];
        short8 o;
        o[0]=f2bf(a.x); o[1]=f2bf(a.y); o[2]=f2bf(a.z); o[3]=f2bf(a.w);
        o[4]=f2bf(b.x); o[5]=f2bf(b.y); o[6]=f2bf(b.z); o[7]=f2bf(b.w);
        *(short8*)(Xb + i * 8) = o;
    }
}

// h -> f32 copy, row-major bf16 (fallback) and fragment-major bf16 (coop, 4bg layout)
__global__ __launch_bounds__(256)
void k_init_h(const float* __restrict__ h0, float* __restrict__ h,
              short* __restrict__ hbRM, short* __restrict__ hbF,
              uint32_t* __restrict__ flags)
{
    int i = blockIdx.x * 256 + threadIdx.x;   // 256 blocks -> 65536
    float v = h0[i];
    h[i] = v;
    short bv = f2bf(v);
    hbRM[i] = bv;
    int b = i >> 10, k = i & 1023;
    int bg = b >> 4, row = b & 15, kk = k >> 5, ksub = (k & 31) >> 3, e = k & 7;
    hbF[bg * 16384 + kk * 512 + row * 32 + ksub * 8 + e] = bv;
    if (i < 8192) flags[i] = 0;
}

// ---------------- phase 1: P = Xb @ Wcat, stored t-major: P[(t*64+b)][n] ----------------
__global__ __launch_bounds__(256)
void k_gemm_x(const short* __restrict__ Xb, const short* __restrict__ WcatT, short* __restrict__ P)
{
    __shared__ short As[128 * 64];
    __shared__ short Bs[128 * 64];
    int tid = threadIdx.x;
    int lane = tid & 63, wave = tid >> 6;
    int i0 = blockIdx.y * 128;    // M block
    int n0 = blockIdx.x * 128;    // N block
    int wrow = (wave >> 1) * 64, wcol = (wave & 1) * 64;
    f32x4 acc[4][4] = {};

    for (int k0 = 0; k0 < KIN; k0 += 64) {
        __syncthreads();
        #pragma unroll
        for (int j = 0; j < 4; j++) {
            int e = (j * 256 + tid) * 8;
            int row = e >> 6, k = e & 63;
            short8 va = *(const short8*)(Xb    + (long)(i0 + row) * KIN + k0 + k);
            short8 vb = *(const short8*)(WcatT + (long)(n0 + row) * KIN + k0 + k);
            int byt = row * 128 + ((k * 2) ^ ((row & 7) << 4));   // XOR swizzle
            *(short8*)((char*)As + byt) = va;
            *(short8*)((char*)Bs + byt) = vb;
        }
        __syncthreads();
        #pragma unroll
        for (int kk = 0; kk < 64; kk += 32) {
            short8 af[4], bfr[4];
            int kel = kk + (lane >> 4) * 8;
            #pragma unroll
            for (int rt = 0; rt < 4; rt++) {
                int row = wrow + rt * 16 + (lane & 15);
                int byt = row * 128 + ((kel * 2) ^ ((row & 7) << 4));
                af[rt] = *(const short8*)((const char*)As + byt);
            }
            #pragma unroll
            for (int ct = 0; ct < 4; ct++) {
                int row = wcol + ct * 16 + (lane & 15);
                int byt = row * 128 + ((kel * 2) ^ ((row & 7) << 4));
                bfr[ct] = *(const short8*)((const char*)Bs + byt);
            }
            #pragma unroll
            for (int rt = 0; rt < 4; rt++)
                #pragma unroll
                for (int ct = 0; ct < 4; ct++)
                    acc[rt][ct] = __builtin_amdgcn_mfma_f32_16x16x32_bf16(af[rt], bfr[ct], acc[rt][ct], 0, 0, 0);
        }
    }
    #pragma unroll
    for (int rt = 0; rt < 4; rt++)
      #pragma unroll
      for (int ct = 0; ct < 4; ct++)
        #pragma unroll
        for (int r = 0; r < 4; r++) {
            int row = i0 + wrow + rt * 16 + (lane >> 4) * 4 + r;   // = b*256 + t
            int prow = ((row & 255) << 6) | (row >> 8);            // t*64 + b
            int col = n0 + wcol + ct * 16 + (lane & 15);
            P[(long)prow * N3 + col] = f2bf(acc[rt][ct][r]);
        }
}

// ---------------- persistent recurrence kernel v7 ----------------
// 256 blocks = 4 bg x 64 cg, 256 thr = 4 waves. Weights LDS-resident; h in wave0 regs.
// All waves poll independently (no post-poll barrier); 2 syncthreads/step total.
// Phase A: all waves load 8 hb frags -> r partials (pbR) + z partials (pbZ) -> SYNC_A;
//          w0: reduce r, rh publish + flag; w1: reduce z -> z_lds (parallel).
// Phase B: all waves load 8 rh frags -> c partials (pbC) -> SYNC_B;
//          w0: reduce c, tanh, h update (regs), hb publish + flag, out stores.
__global__ __launch_bounds__(RTHR)
void k_recur7(const short* __restrict__ UcatT, const short* __restrict__ UcT,
              const short* __restrict__ P, const float* __restrict__ hG,
              char* __restrict__ hbF, char* __restrict__ rhF,
              uint32_t* __restrict__ flags, float* __restrict__ out)
{
    __shared__ short wbuf[49152];     // 96KB: tau(3) x kk(32) x 1KB frag (lane-order)
    __shared__ float pbR[1024];       // r partials: 4 waves x 64 lanes x f32x4
    __shared__ float pbZ[1024];       // z partials
    __shared__ float pbC[1024];       // c partials
    __shared__ float z_lds[256];
    __shared__ short tscr[320];       // wave0 transpose scratch

    const int tid  = threadIdx.x;
    const int lane = tid & 63, w = tid >> 6;
    const int col16 = lane & 15, rquad = (lane >> 4) * 4;
    const int bg = blockIdx.x >> 6;
    const int cg = blockIdx.x & 63;
    const int c0 = cg * 16;
    const int grpbase = bg * 64;

    // ---- one-time: weights -> LDS (fragment, lane-order) ----
    #pragma unroll 4
    for (int i = 0; i < 24; i++) {
        int c = tid + i * 256;
        int tau = c >> 11, cc = c & 2047;
        int kk = cc >> 6, l = cc & 63;
        const short* srcp;
        if (tau == 0)      srcp = UcatT + (c0 + (l & 15)) * 1024 + kk * 32 + ((l >> 4) & 3) * 8;
        else if (tau == 1) srcp = UcatT + (1024 + c0 + (l & 15)) * 1024 + kk * 32 + ((l >> 4) & 3) * 8;
        else               srcp = UcT   + (c0 + (l & 15)) * 1024 + kk * 32 + ((l >> 4) & 3) * 8;
        *(short8*)((char*)wbuf + c * 16) = *(const short8*)srcp;
    }
    // h -> wave0 registers (C-layout: lane holds rows rquad..+3 at col col16)
    f32x4 hreg = {};
    if (w == 0) {
        #pragma unroll
        for (int r = 0; r < 4; r++)
            hreg[r] = hG[(bg * 16 + rquad + r) * 1024 + c0 + col16];
    }
    __syncthreads();

    // per-wave K-split bases (frags kk = w*8 .. w*8+7)
    const char* aA  = hbF + bg * 32768 + (w * 8) * 1024 + (lane & 15) * 64 + (lane >> 4) * 16;
    const char* aB  = rhF + bg * 32768 + (w * 8) * 1024 + (lane & 15) * 64 + (lane >> 4) * 16;
    const char* wbR = (const char*)wbuf + (w * 8) * 1024 + lane * 16;
    const char* wbZ = (const char*)wbuf + 32768 + (w * 8) * 1024 + lane * 16;
    const char* wbC = (const char*)wbuf + 65536 + (w * 8) * 1024 + lane * 16;
    const int kkp = c0 >> 5, halfp = (c0 >> 4) & 1;
    float* mypbR = pbR + w * 256 + lane * 4;
    float* mypbZ = pbZ + w * 256 + lane * 4;
    float* mypbC = pbC + w * 256 + lane * 4;

    uint32_t pr[4], pz[4], pc[4];
    {   // prologue: prefetch P(0)
        const char* Pb = (const char*)(P + (long)(bg * 16) * N3 + c0 + col16);
        if (w == 0) {
            #pragma unroll
            for (int r = 0; r < 4; r++) CLDU16(pr[r], Pb + (long)(rquad + r) * N3 * 2);
            #pragma unroll
            for (int r = 0; r < 4; r++) CLDU16(pc[r], Pb + ((long)(rquad + r) * N3 + 2048) * 2);
        } else if (w == 1) {
            #pragma unroll
            for (int r = 0; r < 4; r++) CLDU16(pz[r], Pb + ((long)(rquad + r) * N3 + 1024) * 2);
        }
    }

    for (int t = 0; t < T_; t++) {
        // ================= phase A =================
        {   // all waves poll for hb(t)
            uint32_t tgt = 2u * t;
            for (;;) {
                uint32_t v = __hip_atomic_load(flags + (grpbase + lane) * 32,
                                               __ATOMIC_RELAXED, __HIP_MEMORY_SCOPE_AGENT);
                if (__all((int)(v >= tgt))) break;
            }
        }
        short8 a[8];
        #pragma unroll
        for (int j = 0; j < 8; j++) CLDC(a[j], aA + j * 1024);
        asm volatile("s_waitcnt vmcnt(0)" ::: "memory");
        __builtin_amdgcn_sched_barrier(0);

        f32x4 accr = {};
        #pragma unroll
        for (int j = 0; j < 8; j++) {
            short8 bw = *(const short8*)(wbR + j * 1024);
            accr = __builtin_amdgcn_mfma_f32_16x16x32_bf16(a[j], bw, accr, 0, 0, 0);
        }
        *(f32x4*)mypbR = accr;
        f32x4 accz = {};
        #pragma unroll
        for (int j = 0; j < 8; j++) {
            short8 bw = *(const short8*)(wbZ + j * 1024);
            accz = __builtin_amdgcn_mfma_f32_16x16x32_bf16(a[j], bw, accz, 0, 0, 0);
        }
        *(f32x4*)mypbZ = accz;
        asm volatile("s_waitcnt lgkmcnt(0)" ::: "memory");
        __syncthreads();                              // SYNC_A

        if (w == 0) {        // r epilogue + rh publish + flag
            f32x4 s = *(const f32x4*)(pbR + lane * 4) + *(const f32x4*)(pbR + 256 + lane * 4)
                    + *(const f32x4*)(pbR + 512 + lane * 4) + *(const f32x4*)(pbR + 768 + lane * 4);
            #pragma unroll
            for (int r = 0; r < 4; r++) {
                float pre = s[r] + u16tof(pr[r]);
                float v = fminf(fmaxf(0.2f * pre + 0.5f, 0.f), 1.f);
                tscr[(rquad + r) * 20 + col16] = f2bf(v * hreg[r]);
            }
            asm volatile("s_waitcnt lgkmcnt(0)" ::: "memory");
            __builtin_amdgcn_sched_barrier(0);
            u64 vv = *(const u64*)((const char*)tscr + (lane & 15) * 40 + (lane >> 4) * 8);
            cst8(rhF + bg * 32768 + kkp * 1024 + (lane & 15) * 64 + halfp * 32 + (lane >> 4) * 8, vv);
            asm volatile("s_waitcnt vmcnt(0)" ::: "memory");
            if (lane == 0)
                __hip_atomic_store(flags + blockIdx.x * 32, 2u * t + 1u,
                                   __ATOMIC_RELAXED, __HIP_MEMORY_SCOPE_AGENT);
        } else if (w == 1) { // z finish (parallel with w0's publish)
            f32x4 sz = *(const f32x4*)(pbZ + lane * 4) + *(const f32x4*)(pbZ + 256 + lane * 4)
                     + *(const f32x4*)(pbZ + 512 + lane * 4) + *(const f32x4*)(pbZ + 768 + lane * 4);
            #pragma unroll
            for (int r = 0; r < 4; r++) {
                float pre = sz[r] + u16tof(pz[r]);
                z_lds[(rquad + r) * 16 + col16] = fminf(fmaxf(0.2f * pre + 0.5f, 0.f), 1.f);
            }
        }

        // ================= phase B =================
        {   // all waves poll for rh(t)
            uint32_t tgt = 2u * t + 1u;
            for (;;) {
                uint32_t v = __hip_atomic_load(flags + (grpbase + lane) * 32,
                                               __ATOMIC_RELAXED, __HIP_MEMORY_SCOPE_AGENT);
                if (__all((int)(v >= tgt))) break;
            }
        }
        #pragma unroll
        for (int j = 0; j < 8; j++) CLDC(a[j], aB + j * 1024);
        asm volatile("s_waitcnt vmcnt(0)" ::: "memory");
        __builtin_amdgcn_sched_barrier(0);

        f32x4 accc = {};
        #pragma unroll
        for (int j = 0; j < 8; j++) {
            short8 bw = *(const short8*)(wbC + j * 1024);
            accc = __builtin_amdgcn_mfma_f32_16x16x32_bf16(a[j], bw, accc, 0, 0, 0);
        }
        *(f32x4*)mypbC = accc;
        asm volatile("s_waitcnt lgkmcnt(0)" ::: "memory");
        __syncthreads();                              // SYNC_B

        if (w == 0) {        // c epilogue + h update (regs) + hb publish + flag + out
            f32x4 s = *(const f32x4*)(pbC + lane * 4) + *(const f32x4*)(pbC + 256 + lane * 4)
                    + *(const f32x4*)(pbC + 512 + lane * 4) + *(const f32x4*)(pbC + 768 + lane * 4);
            #pragma unroll
            for (int r = 0; r < 4; r++) {
                float pre = s[r] + u16tof(pc[r]);
                float hc = tanhf(pre);
                float z  = z_lds[(rquad + r) * 16 + col16];
                float hn = (1.f - z) * hreg[r] + z * hc;
                hreg[r] = hn;
                tscr[(rquad + r) * 20 + col16] = f2bf(hn);
            }
            asm volatile("s_waitcnt lgkmcnt(0)" ::: "memory");
            __builtin_amdgcn_sched_barrier(0);
            u64 vv = *(const u64*)((const char*)tscr + (lane & 15) * 40 + (lane >> 4) * 8);
            cst8(hbF + bg * 32768 + kkp * 1024 + (lane & 15) * 64 + halfp * 32 + (lane >> 4) * 8, vv);
            asm volatile("s_waitcnt vmcnt(0)" ::: "memory");
            if (lane == 0)
                __hip_atomic_store(flags + blockIdx.x * 32, 2u * t + 2u,
                                   __ATOMIC_RELAXED, __HIP_MEMORY_SCOPE_AGENT);
            // out stores AFTER the flag (off the critical path)
            #pragma unroll
            for (int r = 0; r < 4; r++)
                out[((long)(bg * 16 + rquad + r) * T_ + t) * 1024 + c0 + col16] = hreg[r];
        }

        {   // prefetch P(t+1) — retires during next poll
            int tn = (t + 1) & 255;
            const char* Pb = (const char*)(P + ((long)tn * 64 + bg * 16) * N3 + c0 + col16);
            if (w == 0) {
                #pragma unroll
                for (int r = 0; r < 4; r++) CLDU16(pr[r], Pb + (long)(rquad + r) * N3 * 2);
                #pragma unroll
                for (int r = 0; r < 4; r++) CLDU16(pc[r], Pb + ((long)(rquad + r) * N3 + 2048) * 2);
            } else if (w == 1) {
                #pragma unroll
                for (int r = 0; r < 4; r++) CLDU16(pz[r], Pb + ((long)(rquad + r) * N3 + 1024) * 2);
            }
        }
    }
}

// ---------------- fallback per-step kernels (row-major hb/rh, t-major P) ----------------
__global__ __launch_bounds__(256)
void k_stepA(const short* __restrict__ hb, const short* __restrict__ UcatT,
             const short* __restrict__ P, const float* __restrict__ h,
             short* __restrict__ rh, float* __restrict__ zbuf, int t)
{
    int lane = threadIdx.x & 63, wave = threadIdx.x >> 6;
    int wid = blockIdx.x * 4 + wave;
    int ct = wid & 127, rt = wid >> 7;
    int r0 = rt * 16, n0 = ct * 16;
    int lrow = lane & 15, lk = (lane >> 4) * 8;
    f32x4 acc = {0.f, 0.f, 0.f, 0.f};
    const short8* Aptr = (const short8*)(hb    + (r0 + lrow) * 1024 + lk);
    const short8* Bptr = (const short8*)(UcatT + (n0 + lrow) * 1024 + lk);
    #pragma unroll 8
    for (int kk = 0; kk < 32; kk++)
        acc = __builtin_amdgcn_mfma_f32_16x16x32_bf16(Aptr[kk * 4], Bptr[kk * 4], acc, 0, 0, 0);

    int col = n0 + (lane & 15);
    int brb = r0 + (lane >> 4) * 4;
    #pragma unroll
    for (int r = 0; r < 4; r++) {
        int b = brb + r;
        float pre = acc[r] + bf2f(P[((long)t * 64 + b) * N3 + col]);
        float v = fminf(fmaxf(0.2f * pre + 0.5f, 0.f), 1.f);
        if (col < 1024)
            rh[b * 1024 + col] = f2bf(v * h[b * 1024 + col]);
        else
            zbuf[b * 1024 + (col - 1024)] = v;
    }
}

__global__ __launch_bounds__(256)
void k_stepB(const short* __restrict__ rh, const short* __restrict__ UcT,
             const short* __restrict__ P, const float* __restrict__ zbuf,
             float* __restrict__ h, short* __restrict__ hb,
             float* __restrict__ out, int t)
{
    int lane = threadIdx.x & 63, wave = threadIdx.x >> 6;
    int wid = blockIdx.x * 4 + wave;
    int ct = wid & 63, rt = wid >> 6;
    int r0 = rt * 16, n0 = ct * 16;
    int lrow = lane & 15, lk = (lane >> 4) * 8;
    f32x4 acc = {0.f, 0.f, 0.f, 0.f};
    const short8* Aptr = (const short8*)(rh  + (r0 + lrow) * 1024 + lk);
    const short8* Bptr = (const short8*)(UcT + (n0 + lrow) * 1024 + lk);
    #pragma unroll 8
    for (int kk = 0; kk < 32; kk++)
        acc = __builtin_amdgcn_mfma_f32_16x16x32_bf16(Aptr[kk * 4], Bptr[kk * 4], acc, 0, 0, 0);

    int col = n0 + (lane & 15);
    int brb = r0 + (lane >> 4) * 4;
    #pragma unroll
    for (int r = 0; r < 4; r++) {
        int b = brb + r;
        float pre = acc[r] + bf2f(P[((long)t * 64 + b) * N3 + 2048 + col]);
        float hc = tanhf(pre);
        float z  = zbuf[b * 1024 + col];
        float ho = h[b * 1024 + col];
        float hn = (1.f - z) * ho + z * hc;
        h[b * 1024 + col]  = hn;
        hb[b * 1024 + col] = f2bf(hn);
        out[((long)b * T_ + t) * 1024 + col] = hn;
    }
}

extern "C" void kernel_launch(void* const* d_in, const int* in_sizes, int n_in,
                              void* d_out, int out_size, void* d_ws, size_t ws_size,
                              hipStream_t stream)
{
    (void)in_sizes; (void)n_in; (void)out_size; (void)ws_size;
    const float* X   = (const float*)d_in[0];
    const float* h0  = (const float*)d_in[1];
    const float* W_r = (const float*)d_in[2];
    const float* U_r = (const float*)d_in[3];
    const float* C_r = (const float*)d_in[4];
    const float* W_z = (const float*)d_in[5];
    const float* U_z = (const float*)d_in[6];
    const float* C_z = (const float*)d_in[7];
    const float* W   = (const float*)d_in[8];
    const float* U   = (const float*)d_in[9];
    const float* C   = (const float*)d_in[10];

    char* ws = (char*)d_ws;
    size_t off = 0;
    short* WcatT = (short*)(ws + off); off += (size_t)N3 * KIN * 2;
    short* UcatT = (short*)(ws + off); off += (size_t)2048 * 1024 * 2;
    short* UcT   = (short*)(ws + off); off += (size_t)1024 * 1024 * 2;
    short* Xb    = (short*)(ws + off); off += (size_t)M_ * KIN * 2;
    short* P     = (short*)(ws + off); off += (size_t)M_ * N3 * 2;
    float* h     = (float*)(ws + off); off += (size_t)B_ * 1024 * 4;
    short* hbRM  = (short*)(ws + off); off += (size_t)B_ * 1024 * 2;
    short* rhRM  = (short*)(ws + off); off += (size_t)B_ * 1024 * 2;
    float* zbuf  = (float*)(ws + off); off += (size_t)B_ * 1024 * 4;
    char*  hbF   = (char*)(ws + off);  off += (size_t)B_ * 1024 * 2;
    char*  rhF   = (char*)(ws + off);  off += (size_t)B_ * 1024 * 2;
    uint32_t* flags = (uint32_t*)(ws + off); off += 32768;

    k_prep_w<<<dim3(32, 32, 9), dim3(32, 8), 0, stream>>>(W_r, U_r, C_r, W_z, U_z, C_z, W, U, C,
                                                          WcatT, UcatT, UcT);
    k_prep_x<<<2048, 256, 0, stream>>>(X, Xb, (long)M_ * KIN / 8);
    k_init_h<<<256, 256, 0, stream>>>(h0, h, hbRM, (short*)hbF, flags);
    k_gemm_x<<<dim3(N3 / 128, M_ / 128), 256, 0, stream>>>(Xb, WcatT, P);

    float* out = (float*)d_out;
    void* args[] = { (void*)&UcatT, (void*)&UcT, (void*)&P, (void*)&h, (void*)&hbF,
                     (void*)&rhF, (void*)&flags, (void*)&out };
    hipError_t e = hipLaunchCooperativeKernel((const void*)k_recur7, dim3(RBLK), dim3(RTHR),
                                              args, 0, stream);
    if (e != hipSuccess) {
        for (int t = 0; t < T_; t++) {
            k_stepA<<<128, 256, 0, stream>>>(hbRM, UcatT, P, h, rhRM, zbuf, t);
            k_stepB<<<64, 256, 0, stream>>>(rhRM, UcT, P, zbuf, h, hbRM, out, t);
        }
    }
}

// Round 14
// 1694.544 us; speedup vs baseline: 1.2278x; 1.2278x over previous
//
#include <hip/hip_runtime.h>
#include <hip/hip_bf16.h>
#include <stdint.h>

#define B_   64
#define T_   256
#define KIN  2048
#define N3   3072
#define M_   16384
#define RBLK 256      // recurrence blocks: 4 bg x 64 cg
#define RTHR 256      // 4 waves

typedef __attribute__((ext_vector_type(8))) short short8;
typedef __attribute__((ext_vector_type(4))) float f32x4;
typedef unsigned long long u64;

static __device__ __forceinline__ float bf2f(short s) {
    union { float f; uint32_t u; } c; c.u = ((uint32_t)(uint16_t)s) << 16; return c.f;
}
static __device__ __forceinline__ float u16tof(uint32_t u) {
    union { float f; uint32_t x; } c; c.x = u << 16; return c.f;
}
static __device__ __forceinline__ short f2bf(float f) {
    union { float f; uint32_t u; } c; c.f = f;
    uint32_t u = c.u;
    uint32_t r = (u + 0x7fffu + ((u >> 16) & 1u)) >> 16;   // round-nearest-even
    return (short)(uint16_t)r;
}

// coherent (L3 coherence point) asm memory ops
#define CLDC(dst, ptr) asm volatile("global_load_dwordx4 %0, %1, off sc0 sc1" : "=v"(dst) : "v"(ptr))
#define CLDU16(dst, ptr) asm volatile("global_load_ushort %0, %1, off"        : "=v"(dst) : "v"(ptr))
static __device__ __forceinline__ void cst8(void* p, u64 v) {
    asm volatile("global_store_dwordx2 %0, %1, off sc0 sc1" :: "v"(p), "v"(v) : "memory");
}

// ---------------- prep: weights -> bf16 transposed layouts ----------------
__global__ __launch_bounds__(256)
void k_prep_w(const float* __restrict__ Wr, const float* __restrict__ Ur, const float* __restrict__ Cr,
              const float* __restrict__ Wz, const float* __restrict__ Uz, const float* __restrict__ Cz,
              const float* __restrict__ Wc, const float* __restrict__ Uc, const float* __restrict__ Cc,
              short* __restrict__ WcatT, short* __restrict__ UcatT, short* __restrict__ UcT)
{
    __shared__ float tile[32][33];
    int m = blockIdx.z;
    const float* src; short* dst; int ld, noff, koff;
    switch (m) {
      case 0: src=Cr; dst=WcatT; ld=KIN;  noff=0;    koff=0;    break;
      case 1: src=Wr; dst=WcatT; ld=KIN;  noff=0;    koff=1024; break;
      case 2: src=Cz; dst=WcatT; ld=KIN;  noff=1024; koff=0;    break;
      case 3: src=Wz; dst=WcatT; ld=KIN;  noff=1024; koff=1024; break;
      case 4: src=Cc; dst=WcatT; ld=KIN;  noff=2048; koff=0;    break;
      case 5: src=Wc; dst=WcatT; ld=KIN;  noff=2048; koff=1024; break;
      case 6: src=Ur; dst=UcatT; ld=1024; noff=0;    koff=0;    break;
      case 7: src=Uz; dst=UcatT; ld=1024; noff=1024; koff=0;    break;
      default: src=Uc; dst=UcT;  ld=1024; noff=0;    koff=0;    break;
    }
    int n0 = blockIdx.x * 32, k0 = blockIdx.y * 32;
    int tx = threadIdx.x, ty = threadIdx.y;      // block (32,8)
    #pragma unroll
    for (int i = 0; i < 32; i += 8)
        tile[ty + i][tx] = src[(long)(k0 + ty + i) * 1024 + (n0 + tx)];
    __syncthreads();
    #pragma unroll
    for (int i = 0; i < 32; i += 8)
        dst[(long)(noff + n0 + ty + i) * ld + koff + k0 + tx] = f2bf(tile[tx][ty + i]);
}

// ---------------- prep: X -> bf16 ----------------
__global__ __launch_bounds__(256)
void k_prep_x(const float* __restrict__ X, short* __restrict__ Xb, long n8)
{
    long i = (long)blockIdx.x * blockDim.x + threadIdx.x;
    long stride = (long)gridDim.x * blockDim.x;
    for (; i < n8; i += stride) {
        const float4* p = (const float4*)(X + i * 8);
        float4 a = p[0], b = p[1];
        short8 o;
        o[0]=f2bf(a.x); o[1]=f2bf(a.y); o[2]=f2bf(a.z); o[3]=f2bf(a.w);
        o[4]=f2bf(b.x); o[5]=f2bf(b.y); o[6]=f2bf(b.z); o[7]=f2bf(b.w);
        *(short8*)(Xb + i * 8) = o;
    }
}

// h -> f32 copy, row-major bf16 (fallback) and fragment-major bf16 (coop, 4bg layout)
__global__ __launch_bounds__(256)
void k_init_h(const float* __restrict__ h0, float* __restrict__ h,
              short* __restrict__ hbRM, short* __restrict__ hbF,
              uint32_t* __restrict__ flags)
{
    int i = blockIdx.x * 256 + threadIdx.x;   // 256 blocks -> 65536
    float v = h0[i];
    h[i] = v;
    short bv = f2bf(v);
    hbRM[i] = bv;
    int b = i >> 10, k = i & 1023;
    int bg = b >> 4, row = b & 15, kk = k >> 5, ksub = (k & 31) >> 3, e = k & 7;
    hbF[bg * 16384 + kk * 512 + row * 32 + ksub * 8 + e] = bv;
    if (i < 8192) flags[i] = 0;
}

// ---------------- phase 1: P = Xb @ Wcat, stored t-major: P[(t*64+b)][n] ----------------
__global__ __launch_bounds__(256)
void k_gemm_x(const short* __restrict__ Xb, const short* __restrict__ WcatT, short* __restrict__ P)
{
    __shared__ short As[128 * 64];
    __shared__ short Bs[128 * 64];
    int tid = threadIdx.x;
    int lane = tid & 63, wave = tid >> 6;
    int i0 = blockIdx.y * 128;    // M block
    int n0 = blockIdx.x * 128;    // N block
    int wrow = (wave >> 1) * 64, wcol = (wave & 1) * 64;
    f32x4 acc[4][4] = {};

    for (int k0 = 0; k0 < KIN; k0 += 64) {
        __syncthreads();
        #pragma unroll
        for (int j = 0; j < 4; j++) {
            int e = (j * 256 + tid) * 8;
            int row = e >> 6, k = e & 63;
            short8 va = *(const short8*)(Xb    + (long)(i0 + row) * KIN + k0 + k);
            short8 vb = *(const short8*)(WcatT + (long)(n0 + row) * KIN + k0 + k);
            int byt = row * 128 + ((k * 2) ^ ((row & 7) << 4));   // XOR swizzle
            *(short8*)((char*)As + byt) = va;
            *(short8*)((char*)Bs + byt) = vb;
        }
        __syncthreads();
        #pragma unroll
        for (int kk = 0; kk < 64; kk += 32) {
            short8 af[4], bfr[4];
            int kel = kk + (lane >> 4) * 8;
            #pragma unroll
            for (int rt = 0; rt < 4; rt++) {
                int row = wrow + rt * 16 + (lane & 15);
                int byt = row * 128 + ((kel * 2) ^ ((row & 7) << 4));
                af[rt] = *(const short8*)((const char*)As + byt);
            }
            #pragma unroll
            for (int ct = 0; ct < 4; ct++) {
                int row = wcol + ct * 16 + (lane & 15);
                int byt = row * 128 + ((kel * 2) ^ ((row & 7) << 4));
                bfr[ct] = *(const short8*)((const char*)Bs + byt);
            }
            #pragma unroll
            for (int rt = 0; rt < 4; rt++)
                #pragma unroll
                for (int ct = 0; ct < 4; ct++)
                    acc[rt][ct] = __builtin_amdgcn_mfma_f32_16x16x32_bf16(af[rt], bfr[ct], acc[rt][ct], 0, 0, 0);
        }
    }
    #pragma unroll
    for (int rt = 0; rt < 4; rt++)
      #pragma unroll
      for (int ct = 0; ct < 4; ct++)
        #pragma unroll
        for (int r = 0; r < 4; r++) {
            int row = i0 + wrow + rt * 16 + (lane >> 4) * 4 + r;   // = b*256 + t
            int prow = ((row & 255) << 6) | (row >> 8);            // t*64 + b
            int col = n0 + wcol + ct * 16 + (lane & 15);
            P[(long)prow * N3 + col] = f2bf(acc[rt][ct][r]);
        }
}

// ---------------- persistent recurrence kernel v8 (R12 skeleton + h-in-regs) ----------------
// 256 blocks = 4 bg x 64 cg, 256 thr = 4 waves. Weights LDS-resident; h in wave0 regs.
// R12-proven sync: w0-only poll + __syncthreads broadcast (4 barriers/step);
// z partials computed after w0's publish section (overlap barrier propagation).
__global__ __launch_bounds__(RTHR)
void k_recur8(const short* __restrict__ UcatT, const short* __restrict__ UcT,
              const short* __restrict__ P, const float* __restrict__ hG,
              char* __restrict__ hbF, char* __restrict__ rhF,
              uint32_t* __restrict__ flags, float* __restrict__ out)
{
    __shared__ short wbuf[49152];     // 96KB: tau(3) x kk(32) x 1KB frag (lane-order)
    __shared__ float pbuf[1024];      // 4KB: 4 waves x 64 lanes x f32x4 (r / c)
    __shared__ float pbuf2[1024];     // 4KB: z partials
    __shared__ float z_lds[256];
    __shared__ short tscr[320];       // wave0: 16 rows x 20 shorts

    const int tid  = threadIdx.x;
    const int lane = tid & 63, w = tid >> 6;
    const int col16 = lane & 15, rquad = (lane >> 4) * 4;
    const int bg = blockIdx.x >> 6;
    const int cg = blockIdx.x & 63;
    const int c0 = cg * 16;
    const int grpbase = bg * 64;

    // ---- one-time: weights -> LDS (fragment, lane-order) ----
    #pragma unroll 4
    for (int i = 0; i < 24; i++) {
        int c = tid + i * 256;                // 0..6143 cells of 16B
        int tau = c >> 11, cc = c & 2047;
        int kk = cc >> 6, l = cc & 63;
        const short* srcp;
        if (tau == 0)      srcp = UcatT + (c0 + (l & 15)) * 1024 + kk * 32 + ((l >> 4) & 3) * 8;
        else if (tau == 1) srcp = UcatT + (1024 + c0 + (l & 15)) * 1024 + kk * 32 + ((l >> 4) & 3) * 8;
        else               srcp = UcT   + (c0 + (l & 15)) * 1024 + kk * 32 + ((l >> 4) & 3) * 8;
        *(short8*)((char*)wbuf + c * 16) = *(const short8*)srcp;
    }
    // h -> wave0 registers (C-layout: lane holds rows rquad..+3 at col col16)
    f32x4 hreg = {};
    if (w == 0) {
        #pragma unroll
        for (int r = 0; r < 4; r++)
            hreg[r] = hG[(bg * 16 + rquad + r) * 1024 + c0 + col16];
    }
    __syncthreads();

    // per-wave K-split bases (frags kk = w*8 .. w*8+7)
    const char* aA  = hbF + bg * 32768 + (w * 8) * 1024 + (lane & 15) * 64 + (lane >> 4) * 16;
    const char* aB  = rhF + bg * 32768 + (w * 8) * 1024 + (lane & 15) * 64 + (lane >> 4) * 16;
    const char* wbR = (const char*)wbuf + (w * 8) * 1024 + lane * 16;
    const char* wbZ = (const char*)wbuf + 32768 + (w * 8) * 1024 + lane * 16;
    const char* wbC = (const char*)wbuf + 65536 + (w * 8) * 1024 + lane * 16;
    const int kkp = c0 >> 5, halfp = (c0 >> 4) & 1;
    float* mypb  = pbuf  + w * 256 + lane * 4;
    float* mypb2 = pbuf2 + w * 256 + lane * 4;

    uint32_t pr[4], pz[4], pc[4];
    {   // prologue: prefetch P(0)
        const char* Pb = (const char*)(P + (long)(bg * 16) * N3 + c0 + col16);
        if (w == 0) {
            #pragma unroll
            for (int r = 0; r < 4; r++) CLDU16(pr[r], Pb + (long)(rquad + r) * N3 * 2);
            #pragma unroll
            for (int r = 0; r < 4; r++) CLDU16(pc[r], Pb + ((long)(rquad + r) * N3 + 2048) * 2);
        } else if (w == 1) {
            #pragma unroll
            for (int r = 0; r < 4; r++) CLDU16(pz[r], Pb + ((long)(rquad + r) * N3 + 1024) * 2);
        }
    }

    for (int t = 0; t < T_; t++) {
        // ================= phase A =================
        if (w == 0) {        // wait for hb(t) (flags >= 2t)
            uint32_t tgt = 2u * t;
            for (;;) {
                uint32_t v = __hip_atomic_load(flags + (grpbase + lane) * 32,
                                               __ATOMIC_RELAXED, __HIP_MEMORY_SCOPE_AGENT);
                if (__all((int)(v >= tgt))) break;
            }
        }
        __syncthreads();

        short8 a[8];
        #pragma unroll
        for (int j = 0; j < 8; j++) CLDC(a[j], aA + j * 1024);
        asm volatile("s_waitcnt vmcnt(0)" ::: "memory");
        __builtin_amdgcn_sched_barrier(0);

        f32x4 acc = {};
        #pragma unroll
        for (int j = 0; j < 8; j++) {
            short8 bw = *(const short8*)(wbR + j * 1024);
            acc = __builtin_amdgcn_mfma_f32_16x16x32_bf16(a[j], bw, acc, 0, 0, 0);
        }
        *(f32x4*)mypb = acc;
        asm volatile("s_waitcnt lgkmcnt(0)" ::: "memory");
        __syncthreads();                              // SYNC_A

        if (w == 0) {        // r epilogue + rh publish + flag arrive
            f32x4 s = *(const f32x4*)(pbuf + lane * 4) + *(const f32x4*)(pbuf + 256 + lane * 4)
                    + *(const f32x4*)(pbuf + 512 + lane * 4) + *(const f32x4*)(pbuf + 768 + lane * 4);
            #pragma unroll
            for (int r = 0; r < 4; r++) {
                float pre = s[r] + u16tof(pr[r]);
                float v = fminf(fmaxf(0.2f * pre + 0.5f, 0.f), 1.f);
                tscr[(rquad + r) * 20 + col16] = f2bf(v * hreg[r]);
            }
            asm volatile("s_waitcnt lgkmcnt(0)" ::: "memory");
            __builtin_amdgcn_sched_barrier(0);
            u64 vv = *(const u64*)((const char*)tscr + (lane & 15) * 40 + (lane >> 4) * 8);
            cst8(rhF + bg * 32768 + kkp * 1024 + (lane & 15) * 64 + halfp * 32 + (lane >> 4) * 8, vv);
            asm volatile("s_waitcnt vmcnt(0)" ::: "memory");
            if (lane == 0)
                __hip_atomic_store(flags + blockIdx.x * 32, 2u * t + 1u,
                                   __ATOMIC_RELAXED, __HIP_MEMORY_SCOPE_AGENT);
        }
        // z partials (overlap with barrier propagation), reuse hb regs
        f32x4 accz = {};
        #pragma unroll
        for (int j = 0; j < 8; j++) {
            short8 bw = *(const short8*)(wbZ + j * 1024);
            accz = __builtin_amdgcn_mfma_f32_16x16x32_bf16(a[j], bw, accz, 0, 0, 0);
        }
        *(f32x4*)mypb2 = accz;
        asm volatile("s_waitcnt lgkmcnt(0)" ::: "memory");

        // ================= phase B =================
        if (w == 0) {        // wait for rh(t) (flags >= 2t+1)
            uint32_t tgt = 2u * t + 1u;
            for (;;) {
                uint32_t v = __hip_atomic_load(flags + (grpbase + lane) * 32,
                                               __ATOMIC_RELAXED, __HIP_MEMORY_SCOPE_AGENT);
                if (__all((int)(v >= tgt))) break;
            }
        }
        __syncthreads();

        #pragma unroll
        for (int j = 0; j < 8; j++) CLDC(a[j], aB + j * 1024);

        if (w == 1) {        // z finish (overlaps frag RT)
            f32x4 sz = *(const f32x4*)(pbuf2 + lane * 4) + *(const f32x4*)(pbuf2 + 256 + lane * 4)
                     + *(const f32x4*)(pbuf2 + 512 + lane * 4) + *(const f32x4*)(pbuf2 + 768 + lane * 4);
            #pragma unroll
            for (int r = 0; r < 4; r++) {
                float pre = sz[r] + u16tof(pz[r]);
                z_lds[(rquad + r) * 16 + col16] = fminf(fmaxf(0.2f * pre + 0.5f, 0.f), 1.f);
            }
        }
        asm volatile("s_waitcnt vmcnt(0)" ::: "memory");
        __builtin_amdgcn_sched_barrier(0);

        f32x4 accc = {};
        #pragma unroll
        for (int j = 0; j < 8; j++) {
            short8 bw = *(const short8*)(wbC + j * 1024);
            accc = __builtin_amdgcn_mfma_f32_16x16x32_bf16(a[j], bw, accc, 0, 0, 0);
        }
        *(f32x4*)mypb = accc;
        asm volatile("s_waitcnt lgkmcnt(0)" ::: "memory");
        __syncthreads();                              // SYNC_B

        if (w == 0) {        // c epilogue + h update (regs) + hb publish + flag + out
            f32x4 s = *(const f32x4*)(pbuf + lane * 4) + *(const f32x4*)(pbuf + 256 + lane * 4)
                    + *(const f32x4*)(pbuf + 512 + lane * 4) + *(const f32x4*)(pbuf + 768 + lane * 4);
            #pragma unroll
            for (int r = 0; r < 4; r++) {
                float pre = s[r] + u16tof(pc[r]);
                float hc = tanhf(pre);
                float z  = z_lds[(rquad + r) * 16 + col16];
                float hn = (1.f - z) * hreg[r] + z * hc;
                hreg[r] = hn;
                tscr[(rquad + r) * 20 + col16] = f2bf(hn);
            }
            asm volatile("s_waitcnt lgkmcnt(0)" ::: "memory");
            __builtin_amdgcn_sched_barrier(0);
            u64 vv = *(const u64*)((const char*)tscr + (lane & 15) * 40 + (lane >> 4) * 8);
            cst8(hbF + bg * 32768 + kkp * 1024 + (lane & 15) * 64 + halfp * 32 + (lane >> 4) * 8, vv);
            asm volatile("s_waitcnt vmcnt(0)" ::: "memory");
            if (lane == 0)
                __hip_atomic_store(flags + blockIdx.x * 32, 2u * t + 2u,
                                   __ATOMIC_RELAXED, __HIP_MEMORY_SCOPE_AGENT);
            // out stores AFTER the flag (off the critical path)
            #pragma unroll
            for (int r = 0; r < 4; r++)
                out[((long)(bg * 16 + rquad + r) * T_ + t) * 1024 + c0 + col16] = hreg[r];
        }

        {   // prefetch P(t+1) — retires during next poll
            int tn = (t + 1) & 255;
            const char* Pb = (const char*)(P + ((long)tn * 64 + bg * 16) * N3 + c0 + col16);
            if (w == 0) {
                #pragma unroll
                for (int r = 0; r < 4; r++) CLDU16(pr[r], Pb + (long)(rquad + r) * N3 * 2);
                #pragma unroll
                for (int r = 0; r < 4; r++) CLDU16(pc[r], Pb + ((long)(rquad + r) * N3 + 2048) * 2);
            } else if (w == 1) {
                #pragma unroll
                for (int r = 0; r < 4; r++) CLDU16(pz[r], Pb + ((long)(rquad + r) * N3 + 1024) * 2);
            }
        }
    }
}

// ---------------- fallback per-step kernels (row-major hb/rh, t-major P) ----------------
__global__ __launch_bounds__(256)
void k_stepA(const short* __restrict__ hb, const short* __restrict__ UcatT,
             const short* __restrict__ P, const float* __restrict__ h,
             short* __restrict__ rh, float* __restrict__ zbuf, int t)
{
    int lane = threadIdx.x & 63, wave = threadIdx.x >> 6;
    int wid = blockIdx.x * 4 + wave;
    int ct = wid & 127, rt = wid >> 7;
    int r0 = rt * 16, n0 = ct * 16;
    int lrow = lane & 15, lk = (lane >> 4) * 8;
    f32x4 acc = {0.f, 0.f, 0.f, 0.f};
    const short8* Aptr = (const short8*)(hb    + (r0 + lrow) * 1024 + lk);
    const short8* Bptr = (const short8*)(UcatT + (n0 + lrow) * 1024 + lk);
    #pragma unroll 8
    for (int kk = 0; kk < 32; kk++)
        acc = __builtin_amdgcn_mfma_f32_16x16x32_bf16(Aptr[kk * 4], Bptr[kk * 4], acc, 0, 0, 0);

    int col = n0 + (lane & 15);
    int brb = r0 + (lane >> 4) * 4;
    #pragma unroll
    for (int r = 0; r < 4; r++) {
        int b = brb + r;
        float pre = acc[r] + bf2f(P[((long)t * 64 + b) * N3 + col]);
        float v = fminf(fmaxf(0.2f * pre + 0.5f, 0.f), 1.f);
        if (col < 1024)
            rh[b * 1024 + col] = f2bf(v * h[b * 1024 + col]);
        else
            zbuf[b * 1024 + (col - 1024)] = v;
    }
}

__global__ __launch_bounds__(256)
void k_stepB(const short* __restrict__ rh, const short* __restrict__ UcT,
             const short* __restrict__ P, const float* __restrict__ zbuf,
             float* __restrict__ h, short* __restrict__ hb,
             float* __restrict__ out, int t)
{
    int lane = threadIdx.x & 63, wave = threadIdx.x >> 6;
    int wid = blockIdx.x * 4 + wave;
    int ct = wid & 63, rt = wid >> 6;
    int r0 = rt * 16, n0 = ct * 16;
    int lrow = lane & 15, lk = (lane >> 4) * 8;
    f32x4 acc = {0.f, 0.f, 0.f, 0.f};
    const short8* Aptr = (const short8*)(rh  + (r0 + lrow) * 1024 + lk);
    const short8* Bptr = (const short8*)(UcT + (n0 + lrow) * 1024 + lk);
    #pragma unroll 8
    for (int kk = 0; kk < 32; kk++)
        acc = __builtin_amdgcn_mfma_f32_16x16x32_bf16(Aptr[kk * 4], Bptr[kk * 4], acc, 0, 0, 0);

    int col = n0 + (lane & 15);
    int brb = r0 + (lane >> 4) * 4;
    #pragma unroll
    for (int r = 0; r < 4; r++) {
        int b = brb + r;
        float pre = acc[r] + bf2f(P[((long)t * 64 + b) * N3 + 2048 + col]);
        float hc = tanhf(pre);
        float z  = zbuf[b * 1024 + col];
        float ho = h[b * 1024 + col];
        float hn = (1.f - z) * ho + z * hc;
        h[b * 1024 + col]  = hn;
        hb[b * 1024 + col] = f2bf(hn);
        out[((long)b * T_ + t) * 1024 + col] = hn;
    }
}

extern "C" void kernel_launch(void* const* d_in, const int* in_sizes, int n_in,
                              void* d_out, int out_size, void* d_ws, size_t ws_size,
                              hipStream_t stream)
{
    (void)in_sizes; (void)n_in; (void)out_size; (void)ws_size;
    const float* X   = (const float*)d_in[0];
    const float* h0  = (const float*)d_in[1];
    const float* W_r = (const float*)d_in[2];
    const float* U_r = (const float*)d_in[3];
    const float* C_r = (const float*)d_in[4];
    const float* W_z = (const float*)d_in[5];
    const float* U_z = (const float*)d_in[6];
    const float* C_z = (const float*)d_in[7];
    const float* W   = (const float*)d_in[8];
    const float* U   = (const float*)d_in[9];
    const float* C   = (const float*)d_in[10];

    char* ws = (char*)d_ws;
    size_t off = 0;
    short* WcatT = (short*)(ws + off); off += (size_t)N3 * KIN * 2;
    short* UcatT = (short*)(ws + off); off += (size_t)2048 * 1024 * 2;
    short* UcT   = (short*)(ws + off); off += (size_t)1024 * 1024 * 2;
    short* Xb    = (short*)(ws + off); off += (size_t)M_ * KIN * 2;
    short* P     = (short*)(ws + off); off += (size_t)M_ * N3 * 2;
    float* h     = (float*)(ws + off); off += (size_t)B_ * 1024 * 4;
    short* hbRM  = (short*)(ws + off); off += (size_t)B_ * 1024 * 2;
    short* rhRM  = (short*)(ws + off); off += (size_t)B_ * 1024 * 2;
    float* zbuf  = (float*)(ws + off); off += (size_t)B_ * 1024 * 4;
    char*  hbF   = (char*)(ws + off);  off += (size_t)B_ * 1024 * 2;
    char*  rhF   = (char*)(ws + off);  off += (size_t)B_ * 1024 * 2;
    uint32_t* flags = (uint32_t*)(ws + off); off += 32768;

    k_prep_w<<<dim3(32, 32, 9), dim3(32, 8), 0, stream>>>(W_r, U_r, C_r, W_z, U_z, C_z, W, U, C,
                                                          WcatT, UcatT, UcT);
    k_prep_x<<<2048, 256, 0, stream>>>(X, Xb, (long)M_ * KIN / 8);
    k_init_h<<<256, 256, 0, stream>>>(h0, h, hbRM, (short*)hbF, flags);
    k_gemm_x<<<dim3(N3 / 128, M_ / 128), 256, 0, stream>>>(Xb, WcatT, P);

    float* out = (float*)d_out;
    void* args[] = { (void*)&UcatT, (void*)&UcT, (void*)&P, (void*)&h, (void*)&hbF,
                     (void*)&rhF, (void*)&flags, (void*)&out };
    hipError_t e = hipLaunchCooperativeKernel((const void*)k_recur8, dim3(RBLK), dim3(RTHR),
                                              args, 0, stream);
    if (e != hipSuccess) {
        for (int t = 0; t < T_; t++) {
            k_stepA<<<128, 256, 0, stream>>>(hbRM, UcatT, P, h, rhRM, zbuf, t);
            k_stepB<<<64, 256, 0, stream>>>(rhRM, UcT, P, zbuf, h, hbRM, out, t);
        }
    }
}